// Round 5
// baseline (636.453 us; speedup 1.0000x reference)
//
#include <hip/hip_runtime.h>
#include <math.h>

#define N 8192
#define IN_F 512
#define OUTF 64
#define TI 16                // rows per WG
#define JSPLIT 8             // j-range splits per row block
#define JCH (N / JSPLIT)     // 1024 cols per wave
#define JT 64                // cols per tile
#define NT (JCH / JT)        // 16 tiles per wave
#define PS 72                // P row stride in f16 (144 B = 36 dw)

typedef _Float16 f16x8 __attribute__((ext_vector_type(8)));
typedef float f32x4 __attribute__((ext_vector_type(4)));

// workspace layout (floats) — ~18.2 MB
#define OFF_HT   0u          // hT: 64x8192 f16 = 262144 float-slots
#define OFF_S    262144u     // s2 = |W_ei| * (h@a1)
#define OFF_T    270336u     // t2 = |W_ei| * (h@a2)
#define OFF_TMAX 278528u     // 16
#define OFF_DEN  294912u     // [8][8192] f32 den partials
#define OFF_NUM  360448u     // [8][8192][64] f32 num partials

#define SB0() __builtin_amdgcn_sched_barrier(0)

__device__ __forceinline__ unsigned enc_f32(float f) {
  unsigned b = __float_as_uint(f);
  return b ^ ((unsigned)((int)b >> 31) | 0x80000000u);
}

// ---------------------------------------------------------------------------
// K1: hT[f][j]=(f16)(input@W)[j][f]; s2=aei*(h@a1); t2=aei*(h@a2); fused tmax.
// (mask pass removed — v6 streams adj directly in k_attn)
// ---------------------------------------------------------------------------
__global__ __launch_bounds__(64) void k_precompute(
    const float* __restrict__ input, const float* __restrict__ W,
    const float* __restrict__ a, const float* __restrict__ W_ei,
    _Float16* __restrict__ hT, float* __restrict__ s2,
    float* __restrict__ t2, unsigned* __restrict__ tmax) {
  const int lane = threadIdx.x;
  const int i0 = blockIdx.x * 4;
  const float aei = fabsf(W_ei[0]);

  float acc[4] = {0.f, 0.f, 0.f, 0.f};
  for (int c = 0; c < IN_F; c += 4) {
    const float w0 = W[(c + 0) * OUTF + lane];
    const float w1 = W[(c + 1) * OUTF + lane];
    const float w2 = W[(c + 2) * OUTF + lane];
    const float w3 = W[(c + 3) * OUTF + lane];
    #pragma unroll
    for (int r = 0; r < 4; r++) {
      const float4 iv = *(const float4*)(input + (size_t)(i0 + r) * IN_F + c);
      acc[r] += iv.x * w0 + iv.y * w1 + iv.z * w2 + iv.w * w3;
    }
  }

  union { _Float16 f[4]; uint2 u; } pk;
  #pragma unroll
  for (int r = 0; r < 4; r++) pk.f[r] = (_Float16)acc[r];
  *(uint2*)(hT + (size_t)lane * N + i0) = pk.u;

  const float a1v = a[lane];
  const float a2v = a[OUTF + lane];
  float tloc = -1e30f;
  #pragma unroll
  for (int r = 0; r < 4; r++) {
    float sv = acc[r] * a1v;
    float tv = acc[r] * a2v;
    #pragma unroll
    for (int off = 1; off < 64; off <<= 1) {
      sv += __shfl_xor(sv, off);
      tv += __shfl_xor(tv, off);
    }
    if (lane == 0) {
      s2[i0 + r] = aei * sv;
      const float t2v = aei * tv;
      t2[i0 + r] = t2v;
      tloc = fmaxf(tloc, t2v);
    }
  }
  if (lane == 0) atomicMax(tmax, enc_f32(tloc));
}

// ---------------------------------------------------------------------------
// K2 v6: barrierless single-wave streaming attention.
//
// R0-R4 evidence: every barrier-synced multi-wave schedule caps at ~2.7 TB/s
// (in-flight bytes sawtooth to ~0 at each rendezvous); cross-iteration L3
// retention is not exploitable (re-poison fill between iterations). Floor =
// stream adj+adj_ad (536 MB) once at max duty cycle.
// v6: one WAVE owns 16 rows x 1024 cols (JSPLIT=8 -> 4096 one-wave WGs,
// 12/CU). The exp->MFMA transpose runs through the WG-private 2.3KB LDS
// P-tile with intra-wave lgkmcnt ordering only — NO s_barrier anywhere.
// Waves free-run: 12 waves x ~8KB prefetch-ahead = ~98KB in flight per CU
// (vs ~22KB Little's-law need), no collective drain points.
// Per tile, FIFO discipline: [fb/t2 (L2)] -> [stream prefetch k+1] ->
// [exp(k): waits streams(k), issued last tile — leaves fb+prefetch in
// flight] -> [MFMA: waits fb, issued BEFORE prefetch — leaves it in flight].
// Cross-WG j-split reduced by k_finish over num/den partials.
// ---------------------------------------------------------------------------
__global__ __launch_bounds__(64, 3) void k_attn(
    const _Float16* __restrict__ hT, const float* __restrict__ s2,
    const float* __restrict__ t2, const unsigned* __restrict__ tmaxp,
    const float* __restrict__ W_si,
    const float* __restrict__ adj_ad, const int* __restrict__ adj,
    float* __restrict__ numP, float* __restrict__ denP) {
  __shared__ __align__(16) _Float16 P0[TI * PS];   // 2304 B
  __shared__ __align__(16) _Float16 P1[TI * PS];   // 2304 B

  const int lane = threadIdx.x;
  const int g = lane >> 4;         // 0..3: k-slice (MFMA) / row group (exp)
  const int cl = lane & 15;        // 0..15: col lane (exp) / row,f (MFMA)
  const int ib = blockIdx.x >> 3;
  const int js = blockIdx.x & 7;
  const int i0 = ib * TI;
  const int jb0 = js * JCH;

  const float asi = fabsf(W_si[0]);
  const unsigned te = *tmaxp;
  const float tm2 = __uint_as_float((te & 0x80000000u) ? (te ^ 0x80000000u) : ~te);

  float s2r[4], MrB[4];
  #pragma unroll
  for (int u = 0; u < 4; u++) {
    s2r[u] = s2[i0 + 4 * u + g];
    const float ym = s2r[u] + tm2;
    MrB[u] = fmaxf(ym, 0.2f * ym) + asi;   // row upper bound on e (ad<=1)
  }

  float S[4] = {0.f, 0.f, 0.f, 0.f};
  f32x4 acc[4];
  #pragma unroll
  for (int nb = 0; nb < 4; nb++) acc[nb] = (f32x4){0.f, 0.f, 0.f, 0.f};

  float4 vaA[4], vaB[4];
  int4 vkA[4], vkB[4];

  // per load instr: 4 rows (4u+g) x 256B contiguous; 8 instrs = one tile
  #define LOADS(kt, va, vk)                                                   \
    {                                                                         \
      const int cb_ = jb0 + (kt) * JT + cl * 4;                               \
      _Pragma("unroll") for (int u = 0; u < 4; u++) {                         \
        const size_t a_ = (size_t)(i0 + 4 * u + g) * N + cb_;                 \
        va[u] = *(const float4*)(adj_ad + a_);                                \
        vk[u] = *(const int4*)(adj + a_);                                     \
      }                                                                       \
    }

  // hT B-frags (L2-resident, 1MB) + t2 vec — issued FIRST each tile so their
  // vmcnt wait never drains the younger stream prefetch
  #define FBLOAD(kt, fb, t2v)                                                 \
    {                                                                         \
      const int jb_ = jb0 + (kt) * JT;                                        \
      t2v = *(const float4*)(t2 + jb_ + cl * 4);                              \
      _Pragma("unroll") for (int ks = 0; ks < 2; ks++)                        \
        _Pragma("unroll") for (int nb = 0; nb < 4; nb++)                      \
            fb[ks][nb] = *(const f16x8*)(hT + (size_t)(nb * 16 + cl) * N +    \
                                         jb_ + ks * 32 + g * 8);              \
    }

  #define EXPW(va, vk, t2v, Pd)                                               \
    {                                                                         \
      const float tv_[4] = {t2v.x, t2v.y, t2v.z, t2v.w};                      \
      _Pragma("unroll") for (int u = 0; u < 4; u++) {                         \
        const float ad_[4] = {va[u].x, va[u].y, va[u].z, va[u].w};            \
        const int mk_[4] = {vk[u].x, vk[u].y, vk[u].z, vk[u].w};              \
        union { _Float16 h[4]; uint2 u2; } pk_;                               \
        _Pragma("unroll") for (int e2 = 0; e2 < 4; e2++) {                    \
          const float y_ = s2r[u] + tv_[e2];                                  \
          const float lr_ = fmaxf(y_, 0.2f * y_);                             \
          const float arg_ = fmaf(asi, ad_[e2], lr_ - MrB[u]);  /* <= 0 */    \
          const float pv_ = (mk_[e2] > 0) ? __expf(arg_) : 0.f;               \
          S[u] += pv_;                                                        \
          pk_.h[e2] = (_Float16)pv_;                                          \
        }                                                                     \
        *(uint2*)(Pd + (4 * u + g) * PS + cl * 4) = pk_.u2;                   \
      }                                                                       \
    }

  #define MFMA4(Ps, fb)                                                       \
    {                                                                         \
      _Pragma("unroll") for (int ks = 0; ks < 2; ks++) {                      \
        const f16x8 fa_ = *(const f16x8*)(Ps + cl * PS + ks * 32 + g * 8);    \
        _Pragma("unroll") for (int nb = 0; nb < 4; nb++)                      \
            acc[nb] = __builtin_amdgcn_mfma_f32_16x16x32_f16(                 \
                fa_, fb[ks][nb], acc[nb], 0, 0, 0);                           \
      }                                                                       \
    }

  LOADS(0, vaA, vkA);
  SB0();

  #pragma unroll 1
  for (int it = 0; it < NT / 2; it++) {
    const int kt = 2 * it;
    {
      f16x8 fb[2][4];
      float4 t2v;
      FBLOAD(kt, fb, t2v);
      SB0();
      LOADS(kt + 1, vaB, vkB);       // prefetch, rides across everything
      SB0();
      EXPW(vaA, vkA, t2v, P0);       // waits streams(kt) only (oldest)
      MFMA4(P0, fb);                 // waits fb (older than prefetch)
    }
    {
      f16x8 fb[2][4];
      float4 t2v;
      FBLOAD(kt + 1, fb, t2v);
      SB0();
      if (it + 1 < NT / 2) LOADS(kt + 2, vaA, vkA);
      SB0();
      EXPW(vaB, vkB, t2v, P1);
      MFMA4(P1, fb);
    }
  }

  // ---- epilogue: row-sum S within 16-lane groups; write partials ----
  #pragma unroll
  for (int u = 0; u < 4; u++) {
    #pragma unroll
    for (int off = 1; off < 16; off <<= 1) S[u] += __shfl_xor(S[u], off);
  }
  if (cl == 0) {
    #pragma unroll
    for (int u = 0; u < 4; u++) denP[js * N + i0 + 4 * u + g] = S[u];
  }
  #pragma unroll
  for (int nb = 0; nb < 4; nb++) {
    #pragma unroll
    for (int reg = 0; reg < 4; reg++) {
      numP[((size_t)js * N + i0 + g * 4 + reg) * OUTF + nb * 16 + cl] =
          acc[nb][reg];
    }
  }
}

// ---------------------------------------------------------------------------
// K3: reduce 8 j-split partials, normalize, elu. 17 MB read — ~4 us.
// ---------------------------------------------------------------------------
__global__ __launch_bounds__(256) void k_finish(
    const float* __restrict__ numP, const float* __restrict__ denP,
    float* __restrict__ out) {
  const int e = blockIdx.x * 256 + threadIdx.x;
  const int i = e >> 6;
  float num = 0.f, den = 0.f;
  #pragma unroll
  for (int js = 0; js < JSPLIT; js++) {
    num += numP[(size_t)js * (N * OUTF) + e];
    den += denP[js * N + i];
  }
  const float x = num / den;
  out[e] = x > 0.f ? x : expm1f(x);
}

// ---------------------------------------------------------------------------
extern "C" void kernel_launch(void* const* d_in, const int* in_sizes, int n_in,
                              void* d_out, int out_size, void* d_ws, size_t ws_size,
                              hipStream_t stream) {
  const float* input  = (const float*)d_in[0];
  const float* W      = (const float*)d_in[1];
  const float* a      = (const float*)d_in[2];
  const float* W_si   = (const float*)d_in[3];
  const float* W_ei   = (const float*)d_in[4];
  const float* adj_ad = (const float*)d_in[5];
  const int*   adj    = (const int*)d_in[6];
  float* out = (float*)d_out;
  float* ws  = (float*)d_ws;

  _Float16* hT   = (_Float16*)(ws + OFF_HT);
  float* s2      = ws + OFF_S;
  float* t2      = ws + OFF_T;
  unsigned* tmax = (unsigned*)(ws + OFF_TMAX);
  float* denP    = ws + OFF_DEN;
  float* numP    = ws + OFF_NUM;

  hipMemsetAsync(tmax, 0, 4, stream);
  k_precompute<<<N / 4, 64, 0, stream>>>(input, W, a, W_ei, hT, s2, t2, tmax);
  k_attn<<<(N / TI) * JSPLIT, 64, 0, stream>>>(hT, s2, t2, tmax, W_si,
                                               adj_ad, adj, numP, denP);
  k_finish<<<N * OUTF / 256, 256, 0, stream>>>(numP, denP, out);
}